// Round 6
// baseline (345.206 us; speedup 1.0000x reference)
//
#include <hip/hip_runtime.h>
#include <hip/hip_bf16.h>
#include <stdint.h>

typedef short bf16x8 __attribute__((ext_vector_type(8)));
typedef float f32x4 __attribute__((ext_vector_type(4)));
typedef unsigned short u16;
typedef unsigned int u32;

#define MFMA(a, b, c) __builtin_amdgcn_mfma_f32_16x16x32_bf16(a, b, c, 0, 0, 0)

#if __has_builtin(__builtin_amdgcn_exp2f)
#define EXP2F(x) __builtin_amdgcn_exp2f(x)
#else
#define EXP2F(x) exp2f(x)
#endif
#if __has_builtin(__builtin_amdgcn_rcpf)
#define RCPF(x) __builtin_amdgcn_rcpf(x)
#else
#define RCPF(x) (1.0f / (x))
#endif

// RNE f32->bf16 via native cast: compiler fuses adjacent pairs into
// v_cvt_pk_bf16_f32 (m240: scalar cast is the fast path; hand asm is slower).
__device__ __forceinline__ u16 f2bf(float f) {
  return __builtin_bit_cast(u16, static_cast<__bf16>(f));
}

// load 8 f32 (32B) and convert to 8 bf16 RNE
__device__ __forceinline__ bf16x8 cvt8(const float* p) {
  const float4 f0 = *(const float4*)p;
  const float4 f1 = *(const float4*)(p + 4);
  bf16x8 r;
  r[0] = (short)f2bf(f0.x); r[1] = (short)f2bf(f0.y);
  r[2] = (short)f2bf(f0.z); r[3] = (short)f2bf(f0.w);
  r[4] = (short)f2bf(f1.x); r[5] = (short)f2bf(f1.y);
  r[6] = (short)f2bf(f1.z); r[7] = (short)f2bf(f1.w);
  return r;
}

// async global->LDS, 16 bytes per lane. LDS dest linear (wave-uniform base +
// lane*16); swizzle applied on the GLOBAL source address instead (m173).
__device__ __forceinline__ void async16(const u16* g, u16* l) {
  __builtin_amdgcn_global_load_lds(
      (const __attribute__((address_space(1))) void*)g,
      (__attribute__((address_space(3))) void*)l, 16, 0, 0);
}

// ---------------------------------------------------------------------------
// One-shot f32 -> bf16 conversion passes (memory-bound, at HBM ceiling).
// ---------------------------------------------------------------------------
__global__ __launch_bounds__(256) void cvt_qk(const float* __restrict__ xq,
                                              const float* __restrict__ xk,
                                              u16* __restrict__ dq,
                                              u16* __restrict__ dk) {
  int b = (int)blockIdx.x;
  const float* s;
  u16* d;
  if (b < 4096) { s = xq; d = dq; } else { s = xk; d = dk; b -= 4096; }
  const size_t off = (size_t)b * 2048 + (size_t)threadIdx.x * 8;
  *(bf16x8*)(d + off) = cvt8(s + off);
}

__global__ __launch_bounds__(256) void cvt_vw(
    const float* __restrict__ xv, const float* __restrict__ wq,
    const float* __restrict__ wk, const float* __restrict__ wv,
    const float* __restrict__ wo, u16* __restrict__ dv, u16* __restrict__ dwq,
    u16* __restrict__ dwk, u16* __restrict__ dwv, u16* __restrict__ dwo) {
  int b = (int)blockIdx.x;
  const float* s;
  u16* d;
  if (b < 4096) { s = xv; d = dv; }
  else if (b < 4608) { s = wq; d = dwq; b -= 4096; }
  else if (b < 5120) { s = wk; d = dwk; b -= 4608; }
  else if (b < 5632) { s = wv; d = dwv; b -= 5120; }
  else { s = wo; d = dwo; b -= 5632; }
  const size_t off = (size_t)b * 2048 + (size_t)threadIdx.x * 8;
  *(bf16x8*)(d + off) = cvt8(s + off);
}

// ---------------------------------------------------------------------------
// Shared 4x4-fragment compute (per-wave 64x64 output). Works for any wm/wn
// wave grid as long as smA/smB rows stay in range and row&7 == la&7.
// ---------------------------------------------------------------------------
__device__ __forceinline__ void gemm_compute(const u16* smA, const u16* smB,
                                             f32x4 acc[4][4], int wm, int wn,
                                             int la, int q) {
#pragma unroll
  for (int ks = 0; ks < 2; ++ks) {
    bf16x8 af[4], bfr[4];
#pragma unroll
    for (int im = 0; im < 4; ++im)
      af[im] = *(const bf16x8*)(smA + (wm * 64 + im * 16 + la) * 64 +
                                (((ks * 4 + q) ^ (la & 7)) * 8));
#pragma unroll
    for (int in = 0; in < 4; ++in)
      bfr[in] = *(const bf16x8*)(smB + (wn * 64 + in * 16 + la) * 64 +
                                 (((ks * 4 + q) ^ (la & 7)) * 8));
#pragma unroll
    for (int im = 0; im < 4; ++im)
#pragma unroll
      for (int in = 0; in < 4; ++in)
        acc[im][in] = MFMA(af[im], bfr[in], acc[im][in]);
  }
}

// ---------------------------------------------------------------------------
// 128x128-tile staging + 2-phase dbuf core (gemm_out). Unchanged from r5.
// ---------------------------------------------------------------------------
__device__ __forceinline__ void stage_gemm(const u16* __restrict__ A,
                                           const u16* __restrict__ W,
                                           u16* smA, u16* smB, int m0, int n0,
                                           int kk, int tid) {
  const int srow = tid >> 3, sblk = tid & 7;
#pragma unroll
  for (int jj = 0; jj < 4; ++jj) {
    const int row = jj * 32 + srow;
    const int sb = (sblk ^ (row & 7)) * 8;  // pre-swizzled global source
    const int ld = (jj * 256 + tid) * 8;    // linear LDS dest
    async16(A + (size_t)(m0 + row) * 1024 + kk * 64 + sb, smA + ld);
    async16(W + (size_t)(n0 + row) * 1024 + kk * 64 + sb, smB + ld);
  }
}

__device__ __forceinline__ void gemm_core(const u16* __restrict__ A,
                                          const u16* __restrict__ W,
                                          u16* smA0, u16* smB0, u16* smA1,
                                          u16* smB1, f32x4 acc[4][4], int m0,
                                          int n0, int tid) {
  const int w = tid >> 6, l = tid & 63;
  const int la = l & 15, q = l >> 4;
  const int wm = w >> 1, wn = w & 1;

  stage_gemm(A, W, smA0, smB0, m0, n0, 0, tid);
  __syncthreads();  // kk=0 tile landed
#pragma unroll 2
  for (int kk = 0; kk < 16; ++kk) {
    u16* ca = (kk & 1) ? smA1 : smA0;
    u16* cb = (kk & 1) ? smB1 : smB0;
    u16* na = (kk & 1) ? smA0 : smA1;
    u16* nb = (kk & 1) ? smB0 : smB1;
    if (kk < 15) stage_gemm(A, W, na, nb, m0, n0, kk + 1, tid);  // in flight
    gemm_compute(ca, cb, acc, wm, wn, la, q);
    __syncthreads();  // drains vmcnt (next tile landed) + reads of ca/cb done
  }
}

// ---------------------------------------------------------------------------
// Merged QKV projection, 256x128 tile, 512 threads (8 waves, 4M x 2N grid,
// per-wave 64x64 = 4x4 frags). Single-buffered LDS 48KB + lb(512,4)
// (VGPR cap 128) -> 2 blocks/CU = 16 waves/CU: one block's barrier drain
// overlaps the other's MFMA (m114/m97 mechanism). Grid (32, 8, 3) = 768.
// z=0: Q -> per-head [bh][n][d], pre-scaled by log2(e)/sqrt(64)
// z=1: K -> per-head [bh][n][d]
// z=2: V -> per-head transposed [bh][d][n]
// ---------------------------------------------------------------------------
__global__ __launch_bounds__(512, 4) void gemm_qkv(
    const u16* __restrict__ Xqb, const u16* __restrict__ Xkb,
    const u16* __restrict__ Xvb, const u16* __restrict__ Wqb,
    const u16* __restrict__ Wkb, const u16* __restrict__ Wvb,
    u16* __restrict__ Qh, u16* __restrict__ Kh, u16* __restrict__ VTp) {
  __shared__ u16 smA[256 * 64];  // 32KB
  __shared__ u16 smB[128 * 64];  // 16KB
  const int z = (int)blockIdx.z;
  const u16* A = (z == 0) ? Xqb : (z == 1) ? Xkb : Xvb;
  const u16* W = (z == 0) ? Wqb : (z == 1) ? Wkb : Wvb;
  u16* out = (z == 0) ? Qh : (z == 1) ? Kh : VTp;
  const float scale = (z == 0) ? 0.18033688011112042f : 1.0f;

  const int tid = (int)threadIdx.x;
  const int w = tid >> 6, l = tid & 63;
  const int la = l & 15, q = l >> 4;
  const int m0 = blockIdx.x * 256, n0 = blockIdx.y * 128;
  const int wm = w >> 1, wn = w & 1;  // wm 0..3 (64-row), wn 0..1 (64-col)
  const int srow = tid >> 3, sblk = tid & 7;

  f32x4 acc[4][4];
#pragma unroll
  for (int i = 0; i < 4; ++i)
#pragma unroll
    for (int j = 0; j < 4; ++j) acc[i][j] = (f32x4){0.f, 0.f, 0.f, 0.f};

  for (int kk = 0; kk < 16; ++kk) {
    __syncthreads();  // prior compute's LDS reads done
    // A: 256 rows x 64 k (4 issues), B: 128 rows x 64 k (2 issues)
#pragma unroll
    for (int jj = 0; jj < 4; ++jj) {
      const int row = jj * 64 + srow;
      const int sb = (sblk ^ (row & 7)) * 8;
      async16(A + (size_t)(m0 + row) * 1024 + kk * 64 + sb,
              smA + (jj * 512 + tid) * 8);
    }
#pragma unroll
    for (int jj = 0; jj < 2; ++jj) {
      const int row = jj * 64 + srow;
      const int sb = (sblk ^ (row & 7)) * 8;
      async16(W + (size_t)(n0 + row) * 1024 + kk * 64 + sb,
              smB + (jj * 512 + tid) * 8);
    }
    __syncthreads();  // vmcnt(0) drain: tile landed
    gemm_compute(smA, smB, acc, wm, wn, la, q);
  }

#pragma unroll
  for (int im = 0; im < 4; ++im) {
    const int mbase = m0 + wm * 64 + im * 16 + q * 4;
#pragma unroll
    for (int in = 0; in < 4; ++in) {
      const int n = n0 + wn * 64 + in * 16 + la;
      if (z == 2) {
        const int b = mbase >> 11, nr = mbase & 2047;
        const int h = n >> 6, d = n & 63;
        uint2 val;
        val.x = (u32)f2bf(acc[im][in][0]) | ((u32)f2bf(acc[im][in][1]) << 16);
        val.y = (u32)f2bf(acc[im][in][2]) | ((u32)f2bf(acc[im][in][3]) << 16);
        *(uint2*)(VTp + ((size_t)((b * 16 + h) * 64 + d)) * 2048 + nr) = val;
      } else {
#pragma unroll
        for (int r = 0; r < 4; ++r) {
          const int mm = mbase + r;
          const int b = mm >> 11, nr = mm & 2047;
          const int h = n >> 6, d = n & 63;
          out[((size_t)((b * 16 + h) * 2048 + nr)) * 64 + d] =
              f2bf(acc[im][in][r] * scale);
        }
      }
    }
  }
}

// Final projection: ctx (bf16, row-major 8192x1024) x Wo^T -> f32 out.
// 128x128 2-phase dbuf (r5 config, unchanged).
__global__ __launch_bounds__(256, 2) void gemm_out(const u16* __restrict__ A,
                                                   const u16* __restrict__ W,
                                                   float* __restrict__ out) {
  __shared__ u16 smA0[128 * 64], smB0[128 * 64];
  __shared__ u16 smA1[128 * 64], smB1[128 * 64];
  const int tid = (int)threadIdx.x;
  const int w = tid >> 6, l = tid & 63;
  const int la = l & 15, q = l >> 4;
  const int m0 = blockIdx.x * 128, n0 = blockIdx.y * 128;
  const int wm = w >> 1, wn = w & 1;

  f32x4 acc[4][4];
#pragma unroll
  for (int i = 0; i < 4; ++i)
#pragma unroll
    for (int j = 0; j < 4; ++j) acc[i][j] = (f32x4){0.f, 0.f, 0.f, 0.f};

  gemm_core(A, W, smA0, smB0, smA1, smB1, acc, m0, n0, tid);

#pragma unroll
  for (int im = 0; im < 4; ++im) {
    const int mbase = m0 + wm * 64 + im * 16 + q * 4;
#pragma unroll
    for (int in = 0; in < 4; ++in) {
      const int n = n0 + wn * 64 + in * 16 + la;
#pragma unroll
      for (int r = 0; r < 4; ++r)
        out[(size_t)(mbase + r) * 1024 + n] = acc[im][in][r];
    }
  }
}

// ---------------------------------------------------------------------------
// Flash attention (r5 config, unchanged). Grid (16 q-tiles, 64 b*h).
// Q PRE-SCALED by log2(e)/sqrt(64) in the Q projection.
// Pipeline per kt (2 barriers, stage latencies hidden under PV):
//   bar#1 (vmcnt drain) -> QK^T -> softmax -> P write -> bar#2 ->
//   issue stage K(kt+1)/V(kt+1) -> rescale + PV
// LDS = 16(K) + 2x16(V dbuf) + 32(P) = 80KB -> 2 blocks/CU.
// ---------------------------------------------------------------------------
__global__ __launch_bounds__(256, 2) void attn_kernel(const u16* __restrict__ Qh,
                                                      const u16* __restrict__ Kh,
                                                      const u16* __restrict__ VT,
                                                      u16* __restrict__ ctx) {
  __shared__ u16 smK[128 * 64];    // K tile, content[row][b] = K[row][b^(row&7)]
  __shared__ u16 smV0[64 * 128];   // V^T tile, content[vr][b] = VT[vr][b^(vr&15)]
  __shared__ u16 smV1[64 * 128];
  __shared__ u16 smP[128 * 128];   // P (i x j), 8-elem blocks swizzled ^(i&15)

  const int tid = (int)threadIdx.x;
  const int w = tid >> 6, l = tid & 63;
  const int la = l & 15, q = l >> 4;
  const int qt = blockIdx.x, bh = blockIdx.y;
  const u16* Qp = Qh + (size_t)bh * (2048 * 64);
  const u16* Kp = Kh + (size_t)bh * (2048 * 64);
  const u16* Vp = VT + (size_t)bh * (64 * 2048);

  // Q fragments (B-operand: n = lane&15 -> q-row, k = q*8+j)
  bf16x8 qf[2][2];
#pragma unroll
  for (int ic = 0; ic < 2; ++ic)
#pragma unroll
    for (int ks = 0; ks < 2; ++ks)
      qf[ic][ks] = *(const bf16x8*)(Qp + (size_t)(qt * 128 + w * 32 + ic * 16 + la) * 64 +
                                    ks * 32 + q * 8);

  f32x4 accO[2][4];
#pragma unroll
  for (int ic = 0; ic < 2; ++ic)
#pragma unroll
    for (int dc = 0; dc < 4; ++dc) accO[ic][dc] = (f32x4){0.f, 0.f, 0.f, 0.f};
  float m_[2] = {-__builtin_inff(), -__builtin_inff()};
  float l_[2] = {0.f, 0.f};
  float alpha_[2];
  bool skip_[2];

  const int srow = tid >> 3, sblk = tid & 7;

  // per-thread staging lambdas
  auto stageK = [&](int kt) {
#pragma unroll
    for (int jj = 0; jj < 4; ++jj) {
      const int krow = jj * 32 + srow;
      const int ksb = (sblk ^ (krow & 7)) * 8;
      async16(Kp + (size_t)(kt * 128 + krow) * 64 + ksb, smK + (jj * 256 + tid) * 8);
    }
  };
  auto stageV = [&](int kt, u16* dst) {
#pragma unroll
    for (int jj = 0; jj < 4; ++jj) {
      const int idx = jj * 256 + tid;
      const int vr = idx >> 4, vb = idx & 15;
      async16(Vp + (size_t)vr * 2048 + kt * 128 + ((vb ^ (vr & 15)) * 8),
              dst + idx * 8);
    }
  };

  stageK(0);
  stageV(0, smV0);

  for (int kt = 0; kt < 16; ++kt) {
    u16* vcur = (kt & 1) ? smV1 : smV0;
    u16* vnxt = (kt & 1) ? smV0 : smV1;
    __syncthreads();  // vmcnt drain: K(kt),V(kt) landed; prior-iter reads done

    // S^T tiles: m = j (8 chunks), n = i (wave's 2 chunks). Q pre-scaled.
    f32x4 st[2][8];
#pragma unroll
    for (int ic = 0; ic < 2; ++ic)
#pragma unroll
      for (int jc = 0; jc < 8; ++jc) st[ic][jc] = (f32x4){0.f, 0.f, 0.f, 0.f};
    __builtin_amdgcn_s_setprio(1);
#pragma unroll
    for (int ks = 0; ks < 2; ++ks) {
      bf16x8 kf[8];
#pragma unroll
      for (int jc = 0; jc < 8; ++jc)
        kf[jc] = *(const bf16x8*)(smK + (jc * 16 + la) * 64 +
                                  (((ks * 4 + q) ^ (la & 7)) * 8));
#pragma unroll
      for (int jc = 0; jc < 8; ++jc)
#pragma unroll
        for (int ic = 0; ic < 2; ++ic)
          st[ic][jc] = MFMA(kf[jc], qf[ic][ks], st[ic][jc]);
    }
    __builtin_amdgcn_s_setprio(0);

    // online softmax; lane owns row i = w*32+ic*16+la, j = jc*16 + q*4 + r
#pragma unroll
    for (int ic = 0; ic < 2; ++ic) {
      float mx = -__builtin_inff();
#pragma unroll
      for (int jc = 0; jc < 8; ++jc)
#pragma unroll
        for (int r = 0; r < 4; ++r) mx = fmaxf(mx, st[ic][jc][r]);
      mx = fmaxf(mx, __shfl_xor(mx, 16));
      mx = fmaxf(mx, __shfl_xor(mx, 32));
      // defer-max: keep old m when tile max is within THR=8 (P bounded by 2^8)
      const bool skip = (bool)__all(mx - m_[ic] <= 8.0f);
      float mnew, al;
      if (skip) { mnew = m_[ic]; al = 1.0f; }
      else { mnew = fmaxf(m_[ic], mx); al = EXP2F(m_[ic] - mnew); }
      skip_[ic] = skip;
      alpha_[ic] = al;
      float rs = 0.f;
      const int i = w * 32 + ic * 16 + la;
#pragma unroll
      for (int jc = 0; jc < 8; ++jc) {
        const float p0 = EXP2F(st[ic][jc][0] - mnew);
        const float p1 = EXP2F(st[ic][jc][1] - mnew);
        const float p2 = EXP2F(st[ic][jc][2] - mnew);
        const float p3 = EXP2F(st[ic][jc][3] - mnew);
        rs += (p0 + p1) + (p2 + p3);
        uint2 val;
        val.x = (u32)f2bf(p0) | ((u32)f2bf(p1) << 16);  // fuses to v_cvt_pk
        val.y = (u32)f2bf(p2) | ((u32)f2bf(p3) << 16);
        const int blk = (jc * 2 + (q >> 1)) ^ la;  // logical 8-blk ^ (i&15)
        *(uint2*)(smP + i * 128 + blk * 8 + (q & 1) * 4) = val;
      }
      rs += __shfl_xor(rs, 16);
      rs += __shfl_xor(rs, 32);
      m_[ic] = mnew;
      l_[ic] = l_[ic] * alpha_[ic] + rs;
    }
    __syncthreads();  // P visible; all smK reads done

    // prefetch next K/V tiles — in flight under rescale+PV
    if (kt < 15) {
      stageK(kt + 1);
      stageV(kt + 1, vnxt);
    }

    // rescale O by alpha (skipped when defer-max held; wave-uniform branch)
#pragma unroll
    for (int ic = 0; ic < 2; ++ic)
      if (!skip_[ic]) {
#pragma unroll
        for (int r = 0; r < 4; ++r) {
          const float a = __shfl(alpha_[ic], q * 4 + r);
#pragma unroll
          for (int dc = 0; dc < 4; ++dc) accO[ic][dc][r] *= a;
        }
      }

    // PV: O[i,d] += sum_j P[i,j] V^T[d,j]
#pragma unroll
    for (int ks = 0; ks < 4; ++ks) {
      bf16x8 pf[2], vf[4];
#pragma unroll
      for (int ic = 0; ic < 2; ++ic)
        pf[ic] = *(const bf16x8*)(smP + (w * 32 + ic * 16 + la) * 128 +
                                  (((ks * 4 + q) ^ la) * 8));
#pragma unroll
      for (int dc = 0; dc < 4; ++dc)
        vf[dc] = *(const bf16x8*)(vcur + (dc * 16 + la) * 128 +
                                  (((ks * 4 + q) ^ la) * 8));
      __builtin_amdgcn_s_setprio(1);
#pragma unroll
      for (int ic = 0; ic < 2; ++ic)
#pragma unroll
        for (int dc = 0; dc < 4; ++dc)
          accO[ic][dc] = MFMA(pf[ic], vf[dc], accO[ic][dc]);
      __builtin_amdgcn_s_setprio(0);
    }
  }

  // epilogue: O / l  (l for row base+t lives in lane t<16)
  const int b = bh >> 4, h = bh & 15;
#pragma unroll
  for (int ic = 0; ic < 2; ++ic)
#pragma unroll
    for (int r = 0; r < 4; ++r) {
      const float inv = RCPF(__shfl(l_[ic], q * 4 + r));
      const size_t rowoff =
          ((size_t)(b * 2048 + qt * 128 + w * 32 + ic * 16 + q * 4 + r)) * 1024 + h * 64;
#pragma unroll
      for (int dc = 0; dc < 4; ++dc)
        ctx[rowoff + dc * 16 + la] = f2bf(accO[ic][dc][r] * inv);
    }
}

// ---------------------------------------------------------------------------
extern "C" void kernel_launch(void* const* d_in, const int* in_sizes, int n_in,
                              void* d_out, int out_size, void* d_ws, size_t ws_size,
                              hipStream_t stream) {
  const float* Xq = (const float*)d_in[0];
  const float* Xk = (const float*)d_in[1];
  const float* Xv = (const float*)d_in[2];
  const float* Wq = (const float*)d_in[3];
  const float* Wk = (const float*)d_in[4];
  const float* Wv = (const float*)d_in[5];
  const float* Wo = (const float*)d_in[6];

  const size_t T = 8388608;   // 4*2048*1024 elems (X/intermediate, bf16)
  const size_t WN = 1048576;  // 1024*1024 elems (W, bf16)
  u16 *Xqb, *Xkb, *Xvb, *Wqb, *Wkb, *Wvb, *Wob, *Qh, *Kh, *VTp, *ctx;
  if (ws_size >= (7 * T + 4 * WN) * sizeof(u16)) {
    u16* ws = (u16*)d_ws;
    Xqb = ws; Xkb = ws + T; Xvb = ws + 2 * T;
    Qh = ws + 3 * T; Kh = ws + 4 * T; VTp = ws + 5 * T; ctx = ws + 6 * T;
    Wqb = ws + 7 * T; Wkb = Wqb + WN; Wvb = Wkb + WN; Wob = Wvb + WN;
  } else {
    // Fallback: reuse dead buffers (harness restores d_in before every launch;
    // kernels serialize on `stream`).
    //   cvt_qk:  Xq,Xk f32 -> d_out halves            (Xq,Xk f32 die)
    //   cvt_vw:  Xv -> Xq-buf[0:T]; W's -> Xq-buf[T:]  (Xv f32 dies)
    //   gemm_qkv: writes Qh/Kh into Xk-buf halves, VT into Xv-buf[0:T]
    //   attn: ctx -> Xv-buf[T:2T]
    //   gemm_out: reads ctx/Wo, writes f32 d_out (Xqb/Xkb dead by then)
    u16* ob = (u16*)d_out;
    u16* bq = (u16*)d_in[0];
    u16* bk = (u16*)d_in[1];
    u16* bv = (u16*)d_in[2];
    Xqb = ob; Xkb = ob + T;
    Xvb = bq; Wqb = bq + T; Wkb = Wqb + WN; Wvb = Wkb + WN; Wob = Wvb + WN;
    Qh = bk; Kh = bk + T;
    VTp = bv; ctx = bv + T;
  }

  hipLaunchKernelGGL(cvt_qk, dim3(8192), dim3(256), 0, stream, Xq, Xk, Xqb, Xkb);
  hipLaunchKernelGGL(cvt_vw, dim3(6144), dim3(256), 0, stream, Xv, Wq, Wk, Wv, Wo,
                     Xvb, Wqb, Wkb, Wvb, Wob);
  hipLaunchKernelGGL(gemm_qkv, dim3(32, 8, 3), dim3(512), 0, stream, Xqb, Xkb, Xvb,
                     Wqb, Wkb, Wvb, Qh, Kh, VTp);
  hipLaunchKernelGGL(attn_kernel, dim3(16, 64), dim3(256), 0, stream, Qh, Kh, VTp, ctx);
  hipLaunchKernelGGL(gemm_out, dim3(64, 8), dim3(256), 0, stream, ctx, Wob, (float*)d_out);
}

// Round 7
// 327.420 us; speedup vs baseline: 1.0543x; 1.0543x over previous
//
#include <hip/hip_runtime.h>
#include <hip/hip_bf16.h>
#include <stdint.h>

typedef short bf16x8 __attribute__((ext_vector_type(8)));
typedef float f32x4 __attribute__((ext_vector_type(4)));
typedef unsigned short u16;
typedef unsigned int u32;

#define MFMA(a, b, c) __builtin_amdgcn_mfma_f32_16x16x32_bf16(a, b, c, 0, 0, 0)

#if __has_builtin(__builtin_amdgcn_exp2f)
#define EXP2F(x) __builtin_amdgcn_exp2f(x)
#else
#define EXP2F(x) exp2f(x)
#endif
#if __has_builtin(__builtin_amdgcn_rcpf)
#define RCPF(x) __builtin_amdgcn_rcpf(x)
#else
#define RCPF(x) (1.0f / (x))
#endif

// RNE f32->bf16 via native cast: compiler fuses adjacent pairs into
// v_cvt_pk_bf16_f32 (m240: scalar cast is the fast path; hand asm is slower).
__device__ __forceinline__ u16 f2bf(float f) {
  return __builtin_bit_cast(u16, static_cast<__bf16>(f));
}

// load 8 f32 (32B) and convert to 8 bf16 RNE
__device__ __forceinline__ bf16x8 cvt8(const float* p) {
  const float4 f0 = *(const float4*)p;
  const float4 f1 = *(const float4*)(p + 4);
  bf16x8 r;
  r[0] = (short)f2bf(f0.x); r[1] = (short)f2bf(f0.y);
  r[2] = (short)f2bf(f0.z); r[3] = (short)f2bf(f0.w);
  r[4] = (short)f2bf(f1.x); r[5] = (short)f2bf(f1.y);
  r[6] = (short)f2bf(f1.z); r[7] = (short)f2bf(f1.w);
  return r;
}

// async global->LDS, 16 bytes per lane. LDS dest linear (wave-uniform base +
// lane*16); swizzle applied on the GLOBAL source address instead (m173).
__device__ __forceinline__ void async16(const u16* g, u16* l) {
  __builtin_amdgcn_global_load_lds(
      (const __attribute__((address_space(1))) void*)g,
      (__attribute__((address_space(3))) void*)l, 16, 0, 0);
}

// ---------------------------------------------------------------------------
// One-shot f32 -> bf16 conversion passes (memory-bound, at HBM ceiling).
// ---------------------------------------------------------------------------
__global__ __launch_bounds__(256) void cvt_qk(const float* __restrict__ xq,
                                              const float* __restrict__ xk,
                                              u16* __restrict__ dq,
                                              u16* __restrict__ dk) {
  int b = (int)blockIdx.x;
  const float* s;
  u16* d;
  if (b < 4096) { s = xq; d = dq; } else { s = xk; d = dk; b -= 4096; }
  const size_t off = (size_t)b * 2048 + (size_t)threadIdx.x * 8;
  *(bf16x8*)(d + off) = cvt8(s + off);
}

__global__ __launch_bounds__(256) void cvt_vw(
    const float* __restrict__ xv, const float* __restrict__ wq,
    const float* __restrict__ wk, const float* __restrict__ wv,
    const float* __restrict__ wo, u16* __restrict__ dv, u16* __restrict__ dwq,
    u16* __restrict__ dwk, u16* __restrict__ dwv, u16* __restrict__ dwo) {
  int b = (int)blockIdx.x;
  const float* s;
  u16* d;
  if (b < 4096) { s = xv; d = dv; }
  else if (b < 4608) { s = wq; d = dwq; b -= 4096; }
  else if (b < 5120) { s = wk; d = dwk; b -= 4608; }
  else if (b < 5632) { s = wv; d = dwv; b -= 5120; }
  else { s = wo; d = dwo; b -= 5632; }
  const size_t off = (size_t)b * 2048 + (size_t)threadIdx.x * 8;
  *(bf16x8*)(d + off) = cvt8(s + off);
}

// ---------------------------------------------------------------------------
// GEMM staging + compute helpers (128x128 tile, BK=64). r5 config.
// ---------------------------------------------------------------------------
__device__ __forceinline__ void stage_gemm(const u16* __restrict__ A,
                                           const u16* __restrict__ W,
                                           u16* smA, u16* smB, int m0, int n0,
                                           int kk, int tid) {
  const int srow = tid >> 3, sblk = tid & 7;
#pragma unroll
  for (int jj = 0; jj < 4; ++jj) {
    const int row = jj * 32 + srow;
    const int sb = (sblk ^ (row & 7)) * 8;  // pre-swizzled global source
    const int ld = (jj * 256 + tid) * 8;    // linear LDS dest
    async16(A + (size_t)(m0 + row) * 1024 + kk * 64 + sb, smA + ld);
    async16(W + (size_t)(n0 + row) * 1024 + kk * 64 + sb, smB + ld);
  }
}

__device__ __forceinline__ void gemm_compute(const u16* smA, const u16* smB,
                                             f32x4 acc[4][4], int wm, int wn,
                                             int la, int q) {
#pragma unroll
  for (int ks = 0; ks < 2; ++ks) {
    bf16x8 af[4], bfr[4];
#pragma unroll
    for (int im = 0; im < 4; ++im)
      af[im] = *(const bf16x8*)(smA + (wm * 64 + im * 16 + la) * 64 +
                                (((ks * 4 + q) ^ (la & 7)) * 8));
#pragma unroll
    for (int in = 0; in < 4; ++in)
      bfr[in] = *(const bf16x8*)(smB + (wn * 64 + in * 16 + la) * 64 +
                                 (((ks * 4 + q) ^ (la & 7)) * 8));
#pragma unroll
    for (int im = 0; im < 4; ++im)
#pragma unroll
      for (int in = 0; in < 4; ++in)
        acc[im][in] = MFMA(af[im], bfr[in], acc[im][in]);
  }
}

// 2-phase double-buffered core (T3 minimum): issue STAGE(kk+1) BEFORE the
// ds_read+MFMA of kk; single __syncthreads per iter.
__device__ __forceinline__ void gemm_core(const u16* __restrict__ A,
                                          const u16* __restrict__ W,
                                          u16* smA0, u16* smB0, u16* smA1,
                                          u16* smB1, f32x4 acc[4][4], int m0,
                                          int n0, int tid) {
  const int w = tid >> 6, l = tid & 63;
  const int la = l & 15, q = l >> 4;
  const int wm = w >> 1, wn = w & 1;

  stage_gemm(A, W, smA0, smB0, m0, n0, 0, tid);
  __syncthreads();  // kk=0 tile landed
#pragma unroll 2
  for (int kk = 0; kk < 16; ++kk) {
    u16* ca = (kk & 1) ? smA1 : smA0;
    u16* cb = (kk & 1) ? smB1 : smB0;
    u16* na = (kk & 1) ? smA0 : smA1;
    u16* nb = (kk & 1) ? smB0 : smB1;
    if (kk < 15) stage_gemm(A, W, na, nb, m0, n0, kk + 1, tid);  // in flight
    gemm_compute(ca, cb, acc, wm, wn, la, q);
    __syncthreads();  // drains vmcnt (next tile landed) + reads of ca/cb done
  }
}

// ---------------------------------------------------------------------------
// Merged QKV projection (r5 config: 128x128 2-phase dbuf, 256 thr, lb(256,2)).
// Grid (64, 8, 3); z selects (A, W, out, mode, scale).
// z=0: Q -> per-head [bh][n][d], pre-scaled by log2(e)/sqrt(64)
// z=1: K -> per-head [bh][n][d]
// z=2: V -> per-head transposed [bh][d][n]
// ---------------------------------------------------------------------------
__global__ __launch_bounds__(256, 2) void gemm_qkv(
    const u16* __restrict__ Xqb, const u16* __restrict__ Xkb,
    const u16* __restrict__ Xvb, const u16* __restrict__ Wqb,
    const u16* __restrict__ Wkb, const u16* __restrict__ Wvb,
    u16* __restrict__ Qh, u16* __restrict__ Kh, u16* __restrict__ VTp) {
  __shared__ u16 smA0[128 * 64], smB0[128 * 64];
  __shared__ u16 smA1[128 * 64], smB1[128 * 64];
  const int z = (int)blockIdx.z;
  const u16* A = (z == 0) ? Xqb : (z == 1) ? Xkb : Xvb;
  const u16* W = (z == 0) ? Wqb : (z == 1) ? Wkb : Wvb;
  u16* out = (z == 0) ? Qh : (z == 1) ? Kh : VTp;
  const float scale = (z == 0) ? 0.18033688011112042f : 1.0f;

  const int tid = (int)threadIdx.x;
  const int w = tid >> 6, l = tid & 63;
  const int la = l & 15, q = l >> 4;
  const int m0 = blockIdx.x * 128, n0 = blockIdx.y * 128;
  const int wm = w >> 1, wn = w & 1;

  f32x4 acc[4][4];
#pragma unroll
  for (int i = 0; i < 4; ++i)
#pragma unroll
    for (int j = 0; j < 4; ++j) acc[i][j] = (f32x4){0.f, 0.f, 0.f, 0.f};

  gemm_core(A, W, smA0, smB0, smA1, smB1, acc, m0, n0, tid);

#pragma unroll
  for (int im = 0; im < 4; ++im) {
    const int mbase = m0 + wm * 64 + im * 16 + q * 4;
#pragma unroll
    for (int in = 0; in < 4; ++in) {
      const int n = n0 + wn * 64 + in * 16 + la;
      if (z == 2) {
        const int b = mbase >> 11, nr = mbase & 2047;
        const int h = n >> 6, d = n & 63;
        uint2 val;
        val.x = (u32)f2bf(acc[im][in][0]) | ((u32)f2bf(acc[im][in][1]) << 16);
        val.y = (u32)f2bf(acc[im][in][2]) | ((u32)f2bf(acc[im][in][3]) << 16);
        *(uint2*)(VTp + ((size_t)((b * 16 + h) * 64 + d)) * 2048 + nr) = val;
      } else {
#pragma unroll
        for (int r = 0; r < 4; ++r) {
          const int mm = mbase + r;
          const int b = mm >> 11, nr = mm & 2047;
          const int h = n >> 6, d = n & 63;
          out[((size_t)((b * 16 + h) * 2048 + nr)) * 64 + d] =
              f2bf(acc[im][in][r] * scale);
        }
      }
    }
  }
}

// Final projection: ctx (bf16, row-major 8192x1024) x Wo^T -> f32 out.
__global__ __launch_bounds__(256, 2) void gemm_out(const u16* __restrict__ A,
                                                   const u16* __restrict__ W,
                                                   float* __restrict__ out) {
  __shared__ u16 smA0[128 * 64], smB0[128 * 64];
  __shared__ u16 smA1[128 * 64], smB1[128 * 64];
  const int tid = (int)threadIdx.x;
  const int w = tid >> 6, l = tid & 63;
  const int la = l & 15, q = l >> 4;
  const int m0 = blockIdx.x * 128, n0 = blockIdx.y * 128;
  const int wm = w >> 1, wn = w & 1;

  f32x4 acc[4][4];
#pragma unroll
  for (int i = 0; i < 4; ++i)
#pragma unroll
    for (int j = 0; j < 4; ++j) acc[i][j] = (f32x4){0.f, 0.f, 0.f, 0.f};

  gemm_core(A, W, smA0, smB0, smA1, smB1, acc, m0, n0, tid);

#pragma unroll
  for (int im = 0; im < 4; ++im) {
    const int mbase = m0 + wm * 64 + im * 16 + q * 4;
#pragma unroll
    for (int in = 0; in < 4; ++in) {
      const int n = n0 + wn * 64 + in * 16 + la;
#pragma unroll
      for (int r = 0; r < 4; ++r)
        out[(size_t)(mbase + r) * 1024 + n] = acc[im][in][r];
    }
  }
}

// ---------------------------------------------------------------------------
// Flash attention (r5 pipeline) + XCD-locality swizzle.
// Flat grid 1024; blocks round-robin XCDs by id%8 (m157), so:
//   xcd = id&7, slot = id>>3, bh = xcd*8 + (slot>>4), qt = slot&15
// puts all 16 q-tiles of a head (which share 512KB K/V) on ONE XCD ->
// K/V become L2-resident (fix for measured 139MB FETCH vs 48MB ideal).
// Bijective: 1024 = 8 * 128, nwg%8 == 0.
// Pipeline per kt: bar#1 (vmcnt drain) -> QK^T -> softmax -> P write ->
// bar#2 -> issue stage K(kt+1)/V(kt+1) -> rescale + PV.
// LDS = 16(K) + 2x16(V dbuf) + 32(P) = 80KB -> 2 blocks/CU.
// ---------------------------------------------------------------------------
__global__ __launch_bounds__(256, 2) void attn_kernel(const u16* __restrict__ Qh,
                                                      const u16* __restrict__ Kh,
                                                      const u16* __restrict__ VT,
                                                      u16* __restrict__ ctx) {
  __shared__ u16 smK[128 * 64];    // K tile, content[row][b] = K[row][b^(row&7)]
  __shared__ u16 smV0[64 * 128];   // V^T tile, content[vr][b] = VT[vr][b^(vr&15)]
  __shared__ u16 smV1[64 * 128];
  __shared__ u16 smP[128 * 128];   // P (i x j), 8-elem blocks swizzled ^(i&15)

  const int tid = (int)threadIdx.x;
  const int w = tid >> 6, l = tid & 63;
  const int la = l & 15, q = l >> 4;
  const int id = (int)blockIdx.x;
  const int slot = id >> 3;
  const int bh = (id & 7) * 8 + (slot >> 4);  // all 16 qt of a head -> one XCD
  const int qt = slot & 15;
  const u16* Qp = Qh + (size_t)bh * (2048 * 64);
  const u16* Kp = Kh + (size_t)bh * (2048 * 64);
  const u16* Vp = VT + (size_t)bh * (64 * 2048);

  // Q fragments (B-operand: n = lane&15 -> q-row, k = q*8+j)
  bf16x8 qf[2][2];
#pragma unroll
  for (int ic = 0; ic < 2; ++ic)
#pragma unroll
    for (int ks = 0; ks < 2; ++ks)
      qf[ic][ks] = *(const bf16x8*)(Qp + (size_t)(qt * 128 + w * 32 + ic * 16 + la) * 64 +
                                    ks * 32 + q * 8);

  f32x4 accO[2][4];
#pragma unroll
  for (int ic = 0; ic < 2; ++ic)
#pragma unroll
    for (int dc = 0; dc < 4; ++dc) accO[ic][dc] = (f32x4){0.f, 0.f, 0.f, 0.f};
  float m_[2] = {-__builtin_inff(), -__builtin_inff()};
  float l_[2] = {0.f, 0.f};
  float alpha_[2];
  bool skip_[2];

  const int srow = tid >> 3, sblk = tid & 7;

  // per-thread staging lambdas
  auto stageK = [&](int kt_) {
#pragma unroll
    for (int jj = 0; jj < 4; ++jj) {
      const int krow = jj * 32 + srow;
      const int ksb = (sblk ^ (krow & 7)) * 8;
      async16(Kp + (size_t)(kt_ * 128 + krow) * 64 + ksb, smK + (jj * 256 + tid) * 8);
    }
  };
  auto stageV = [&](int kt_, u16* dst) {
#pragma unroll
    for (int jj = 0; jj < 4; ++jj) {
      const int idx = jj * 256 + tid;
      const int vr = idx >> 4, vb = idx & 15;
      async16(Vp + (size_t)vr * 2048 + kt_ * 128 + ((vb ^ (vr & 15)) * 8),
              dst + idx * 8);
    }
  };

  stageK(0);
  stageV(0, smV0);

  for (int kt = 0; kt < 16; ++kt) {
    u16* vcur = (kt & 1) ? smV1 : smV0;
    u16* vnxt = (kt & 1) ? smV0 : smV1;
    __syncthreads();  // vmcnt drain: K(kt),V(kt) landed; prior-iter reads done

    // S^T tiles: m = j (8 chunks), n = i (wave's 2 chunks). Q pre-scaled.
    f32x4 st[2][8];
#pragma unroll
    for (int ic = 0; ic < 2; ++ic)
#pragma unroll
      for (int jc = 0; jc < 8; ++jc) st[ic][jc] = (f32x4){0.f, 0.f, 0.f, 0.f};
    __builtin_amdgcn_s_setprio(1);
#pragma unroll
    for (int ks = 0; ks < 2; ++ks) {
      bf16x8 kf[8];
#pragma unroll
      for (int jc = 0; jc < 8; ++jc)
        kf[jc] = *(const bf16x8*)(smK + (jc * 16 + la) * 64 +
                                  (((ks * 4 + q) ^ (la & 7)) * 8));
#pragma unroll
      for (int jc = 0; jc < 8; ++jc)
#pragma unroll
        for (int ic = 0; ic < 2; ++ic)
          st[ic][jc] = MFMA(kf[jc], qf[ic][ks], st[ic][jc]);
    }
    __builtin_amdgcn_s_setprio(0);

    // online softmax; lane owns row i = w*32+ic*16+la, j = jc*16 + q*4 + r
#pragma unroll
    for (int ic = 0; ic < 2; ++ic) {
      float mx = -__builtin_inff();
#pragma unroll
      for (int jc = 0; jc < 8; ++jc)
#pragma unroll
        for (int r = 0; r < 4; ++r) mx = fmaxf(mx, st[ic][jc][r]);
      mx = fmaxf(mx, __shfl_xor(mx, 16));
      mx = fmaxf(mx, __shfl_xor(mx, 32));
      // defer-max: keep old m when tile max is within THR=8 (P bounded by 2^8)
      const bool skip = (bool)__all(mx - m_[ic] <= 8.0f);
      float mnew, al;
      if (skip) { mnew = m_[ic]; al = 1.0f; }
      else { mnew = fmaxf(m_[ic], mx); al = EXP2F(m_[ic] - mnew); }
      skip_[ic] = skip;
      alpha_[ic] = al;
      float rs = 0.f;
      const int i = w * 32 + ic * 16 + la;
#pragma unroll
      for (int jc = 0; jc < 8; ++jc) {
        const float p0 = EXP2F(st[ic][jc][0] - mnew);
        const float p1 = EXP2F(st[ic][jc][1] - mnew);
        const float p2 = EXP2F(st[ic][jc][2] - mnew);
        const float p3 = EXP2F(st[ic][jc][3] - mnew);
        rs += (p0 + p1) + (p2 + p3);
        uint2 val;
        val.x = (u32)f2bf(p0) | ((u32)f2bf(p1) << 16);  // fuses to v_cvt_pk
        val.y = (u32)f2bf(p2) | ((u32)f2bf(p3) << 16);
        const int blk = (jc * 2 + (q >> 1)) ^ la;  // logical 8-blk ^ (i&15)
        *(uint2*)(smP + i * 128 + blk * 8 + (q & 1) * 4) = val;
      }
      rs += __shfl_xor(rs, 16);
      rs += __shfl_xor(rs, 32);
      m_[ic] = mnew;
      l_[ic] = l_[ic] * alpha_[ic] + rs;
    }
    __syncthreads();  // P visible; all smK reads done

    // prefetch next K/V tiles — in flight under rescale+PV
    if (kt < 15) {
      stageK(kt + 1);
      stageV(kt + 1, vnxt);
    }

    // rescale O by alpha (skipped when defer-max held; wave-uniform branch)
#pragma unroll
    for (int ic = 0; ic < 2; ++ic)
      if (!skip_[ic]) {
#pragma unroll
        for (int r = 0; r < 4; ++r) {
          const float a = __shfl(alpha_[ic], q * 4 + r);
#pragma unroll
          for (int dc = 0; dc < 4; ++dc) accO[ic][dc][r] *= a;
        }
      }

    // PV: O[i,d] += sum_j P[i,j] V^T[d,j]
#pragma unroll
    for (int ks = 0; ks < 4; ++ks) {
      bf16x8 pf[2], vf[4];
#pragma unroll
      for (int ic = 0; ic < 2; ++ic)
        pf[ic] = *(const bf16x8*)(smP + (w * 32 + ic * 16 + la) * 128 +
                                  (((ks * 4 + q) ^ la) * 8));
#pragma unroll
      for (int dc = 0; dc < 4; ++dc)
        vf[dc] = *(const bf16x8*)(vcur + (dc * 16 + la) * 128 +
                                  (((ks * 4 + q) ^ la) * 8));
      __builtin_amdgcn_s_setprio(1);
#pragma unroll
      for (int ic = 0; ic < 2; ++ic)
#pragma unroll
        for (int dc = 0; dc < 4; ++dc)
          accO[ic][dc] = MFMA(pf[ic], vf[dc], accO[ic][dc]);
      __builtin_amdgcn_s_setprio(0);
    }
  }

  // epilogue: O / l  (l for row base+t lives in lane t<16)
  const int b = bh >> 4, h = bh & 15;
#pragma unroll
  for (int ic = 0; ic < 2; ++ic)
#pragma unroll
    for (int r = 0; r < 4; ++r) {
      const float inv = RCPF(__shfl(l_[ic], q * 4 + r));
      const size_t rowoff =
          ((size_t)(b * 2048 + qt * 128 + w * 32 + ic * 16 + q * 4 + r)) * 1024 + h * 64;
#pragma unroll
      for (int dc = 0; dc < 4; ++dc)
        ctx[rowoff + dc * 16 + la] = f2bf(accO[ic][dc][r] * inv);
    }
}

// ---------------------------------------------------------------------------
extern "C" void kernel_launch(void* const* d_in, const int* in_sizes, int n_in,
                              void* d_out, int out_size, void* d_ws, size_t ws_size,
                              hipStream_t stream) {
  const float* Xq = (const float*)d_in[0];
  const float* Xk = (const float*)d_in[1];
  const float* Xv = (const float*)d_in[2];
  const float* Wq = (const float*)d_in[3];
  const float* Wk = (const float*)d_in[4];
  const float* Wv = (const float*)d_in[5];
  const float* Wo = (const float*)d_in[6];

  const size_t T = 8388608;   // 4*2048*1024 elems (X/intermediate, bf16)
  const size_t WN = 1048576;  // 1024*1024 elems (W, bf16)
  u16 *Xqb, *Xkb, *Xvb, *Wqb, *Wkb, *Wvb, *Wob, *Qh, *Kh, *VTp, *ctx;
  if (ws_size >= (7 * T + 4 * WN) * sizeof(u16)) {
    u16* ws = (u16*)d_ws;
    Xqb = ws; Xkb = ws + T; Xvb = ws + 2 * T;
    Qh = ws + 3 * T; Kh = ws + 4 * T; VTp = ws + 5 * T; ctx = ws + 6 * T;
    Wqb = ws + 7 * T; Wkb = Wqb + WN; Wvb = Wkb + WN; Wob = Wvb + WN;
  } else {
    // Fallback: reuse dead buffers (harness restores d_in before every launch;
    // kernels serialize on `stream`).
    //   cvt_qk:  Xq,Xk f32 -> d_out halves            (Xq,Xk f32 die)
    //   cvt_vw:  Xv -> Xq-buf[0:T]; W's -> Xq-buf[T:]  (Xv f32 dies)
    //   gemm_qkv: writes Qh/Kh into Xk-buf halves, VT into Xv-buf[0:T]
    //   attn: ctx -> Xv-buf[T:2T]
    //   gemm_out: reads ctx/Wo, writes f32 d_out (Xqb/Xkb dead by then)
    u16* ob = (u16*)d_out;
    u16* bq = (u16*)d_in[0];
    u16* bk = (u16*)d_in[1];
    u16* bv = (u16*)d_in[2];
    Xqb = ob; Xkb = ob + T;
    Xvb = bq; Wqb = bq + T; Wkb = Wqb + WN; Wvb = Wkb + WN; Wob = Wvb + WN;
    Qh = bk; Kh = bk + T;
    VTp = bv; ctx = bv + T;
  }

  hipLaunchKernelGGL(cvt_qk, dim3(8192), dim3(256), 0, stream, Xq, Xk, Xqb, Xkb);
  hipLaunchKernelGGL(cvt_vw, dim3(6144), dim3(256), 0, stream, Xv, Wq, Wk, Wv, Wo,
                     Xvb, Wqb, Wkb, Wvb, Wob);
  hipLaunchKernelGGL(gemm_qkv, dim3(64, 8, 3), dim3(256), 0, stream, Xqb, Xkb, Xvb,
                     Wqb, Wkb, Wvb, Qh, Kh, VTp);
  hipLaunchKernelGGL(attn_kernel, dim3(1024), dim3(256), 0, stream, Qh, Kh, VTp, ctx);
  hipLaunchKernelGGL(gemm_out, dim3(64, 8), dim3(256), 0, stream, ctx, Wob, (float*)d_out);
}